// Round 1
// baseline (1809.821 us; speedup 1.0000x reference)
//
#include <hip/hip_runtime.h>

#define D_DIM 256
#define K_CODES 1024

__device__ __forceinline__ const float4& ld4(const float* p) {
    return *reinterpret_cast<const float4*>(p);
}
__device__ __forceinline__ void st4(float* p, const float4& v) {
    *reinterpret_cast<float4*>(p) = v;
}

// ---------------------------------------------------------------------------
// Kernel 0: per-code squared norms ||e_k||^2
// one wave per code (64 lanes x 4 floats = 256 dims)
// ---------------------------------------------------------------------------
__global__ __launch_bounds__(256)
void enorm_kernel(const float* __restrict__ emb, float* __restrict__ enorm) {
    int gid = blockIdx.x * blockDim.x + threadIdx.x;
    int k = gid >> 6;
    int lane = gid & 63;
    if (k >= K_CODES) return;
    float4 v = ld4(emb + (size_t)k * D_DIM + lane * 4);
    float s = v.x * v.x + v.y * v.y + v.z * v.z + v.w * v.w;
    #pragma unroll
    for (int off = 32; off; off >>= 1) s += __shfl_down(s, off);
    if (lane == 0) enorm[k] = s;
}

// ---------------------------------------------------------------------------
// Kernel 1: fused distance-GEMM + argmin.
// Block = 256 threads (16x16), tile = 128 rows x 128 codes, d-chunks of 32.
// Each thread: 8 rows x 8 codes register tile, float4 LDS reads.
// dist = ||e||^2 - 2*x.e  (x^2 term constant per row -> argmin invariant)
// ---------------------------------------------------------------------------
__global__ __launch_bounds__(256, 2)
void argmin_kernel(const float* __restrict__ x, const float* __restrict__ emb,
                   const float* __restrict__ enorm,
                   int* __restrict__ idx_out, float* __restrict__ idxf_out) {
    // pitch 36 floats: 16B-aligned rows, consecutive rows hit distinct banks
    __shared__ __align__(16) float xs[128][36];
    __shared__ __align__(16) float es[128][36];
    const int t = threadIdx.x;
    const int tx = t & 15;
    const int ty = t >> 4;
    const long base = (long)blockIdx.x * 128;

    float best[8];
    int bidx[8];
    #pragma unroll
    for (int i = 0; i < 8; ++i) { best[i] = 3.4e38f; bidx[i] = 0; }

    #pragma unroll 1
    for (int ct = 0; ct < K_CODES / 128; ++ct) {
        float acc[8][8];
        #pragma unroll
        for (int i = 0; i < 8; ++i)
            #pragma unroll
            for (int j = 0; j < 8; ++j) acc[i][j] = 0.0f;

        #pragma unroll 1
        for (int dt = 0; dt < D_DIM / 32; ++dt) {
            __syncthreads();   // previous-iteration readers done
            #pragma unroll
            for (int k2 = 0; k2 < 4; ++k2) {
                int f = t + k2 * 256;          // 1024 float4 per tile
                int r = f >> 3;                // 8 float4 per row of 32 dims
                int c4 = f & 7;
                float4 xv = ld4(x + (base + r) * D_DIM + dt * 32 + c4 * 4);
                float4 ev = ld4(emb + (size_t)(ct * 128 + r) * D_DIM + dt * 32 + c4 * 4);
                st4(&xs[r][c4 * 4], xv);
                st4(&es[r][c4 * 4], ev);
            }
            __syncthreads();
            #pragma unroll
            for (int d4 = 0; d4 < 8; ++d4) {
                float4 xv[8], ev[8];
                #pragma unroll
                for (int i = 0; i < 8; ++i) xv[i] = ld4(&xs[ty + 16 * i][d4 * 4]);
                #pragma unroll
                for (int j = 0; j < 8; ++j) ev[j] = ld4(&es[tx + 16 * j][d4 * 4]);
                #pragma unroll
                for (int i = 0; i < 8; ++i)
                    #pragma unroll
                    for (int j = 0; j < 8; ++j) {
                        acc[i][j] = fmaf(xv[i].x, ev[j].x, acc[i][j]);
                        acc[i][j] = fmaf(xv[i].y, ev[j].y, acc[i][j]);
                        acc[i][j] = fmaf(xv[i].z, ev[j].z, acc[i][j]);
                        acc[i][j] = fmaf(xv[i].w, ev[j].w, acc[i][j]);
                    }
            }
        }
        // fold this code tile into running (min, argmin); ascending c order
        #pragma unroll
        for (int j = 0; j < 8; ++j) {
            int c = ct * 128 + tx + 16 * j;
            float en = enorm[c];
            #pragma unroll
            for (int i = 0; i < 8; ++i) {
                float dist = en - 2.0f * acc[i][j];
                if (dist < best[i]) { best[i] = dist; bidx[i] = c; }
            }
        }
    }

    // reduce across the 16 tx-lanes sharing each row (within one wave)
    #pragma unroll
    for (int i = 0; i < 8; ++i) {
        float bv = best[i];
        int bi = bidx[i];
        #pragma unroll
        for (int off = 1; off < 16; off <<= 1) {
            float ov = __shfl_xor(bv, off);
            int oi = __shfl_xor(bi, off);
            if (ov < bv || (ov == bv && oi < bi)) { bv = ov; bi = oi; }
        }
        if (tx == 0) {
            long row = base + ty + 16 * i;
            idx_out[row] = bi;
            idxf_out[row] = (float)bi;
        }
    }
}

// ---------------------------------------------------------------------------
// Kernel 2: gather quantized, write straight-through output, loss partials,
// EMA scatter (atomics into embedding_sum / counts).
// One wave per row-chunk; 4 waves per block.
// ---------------------------------------------------------------------------
__global__ __launch_bounds__(256)
void quant_scatter_kernel(const float* __restrict__ x, const float* __restrict__ emb,
                          const int* __restrict__ idx, float* __restrict__ qst_out,
                          float* __restrict__ embsum, float* __restrict__ counts,
                          float* __restrict__ partials, int rows_per_wave, int nrows) {
    const int t = threadIdx.x;
    const int lane = t & 63;
    const int wid = t >> 6;
    const long gw = (long)blockIdx.x * 4 + wid;
    float lsum = 0.0f;
    for (int rr = 0; rr < rows_per_wave; ++rr) {
        long row = gw * rows_per_wave + rr;
        if (row >= nrows) break;
        int k = idx[row];
        float4 xv = ld4(x + row * D_DIM + lane * 4);
        float4 qv = ld4(emb + (size_t)k * D_DIM + lane * 4);
        float4 o;   // x + (q - x), exactly as the reference's STE computes it
        o.x = xv.x + (qv.x - xv.x);
        o.y = xv.y + (qv.y - xv.y);
        o.z = xv.z + (qv.z - xv.z);
        o.w = xv.w + (qv.w - xv.w);
        st4(qst_out + row * D_DIM + lane * 4, o);
        float dx = xv.x - qv.x, dy = xv.y - qv.y, dz = xv.z - qv.z, dw = xv.w - qv.w;
        lsum += dx * dx + dy * dy + dz * dz + dw * dw;
        float* es = embsum + (size_t)k * D_DIM + lane * 4;
        atomicAdd(es + 0, xv.x);
        atomicAdd(es + 1, xv.y);
        atomicAdd(es + 2, xv.z);
        atomicAdd(es + 3, xv.w);
        if (lane == 0) atomicAdd(counts + k, 1.0f);
    }
    #pragma unroll
    for (int off = 32; off; off >>= 1) lsum += __shfl_down(lsum, off);
    __shared__ float wsum[4];
    if (lane == 0) wsum[wid] = lsum;
    __syncthreads();
    if (t == 0) partials[blockIdx.x] = wsum[0] + wsum[1] + wsum[2] + wsum[3];
}

// ---------------------------------------------------------------------------
// Kernel 3: cluster-size EMA + Laplace-smoothed denominator (one block)
// ---------------------------------------------------------------------------
__global__ __launch_bounds__(1024)
void cs_kernel(const float* __restrict__ cs_in, const float* __restrict__ counts,
               float* __restrict__ ncs_out, float* __restrict__ cs_ws, int K) {
    const float DECAY = 0.99f, OMD = 0.01f, EPSF = 1e-5f;
    int t = threadIdx.x;
    float ncs = 0.0f;
    if (t < K) {
        ncs = cs_in[t] * DECAY + counts[t] * OMD;
        ncs_out[t] = ncs;
    }
    float s = ncs;
    #pragma unroll
    for (int off = 32; off; off >>= 1) s += __shfl_down(s, off);
    __shared__ float red[16];
    __shared__ float n_sh;
    if ((t & 63) == 0) red[t >> 6] = s;
    __syncthreads();
    if (t == 0) {
        float n = 0.0f;
        for (int i = 0; i < (int)(blockDim.x >> 6); ++i) n += red[i];
        n_sh = n;
    }
    __syncthreads();
    if (t < K) {
        float n = n_sh;
        cs_ws[t] = (ncs + EPSF) / (n + (float)K * EPSF) * n;
    }
}

// ---------------------------------------------------------------------------
// Kernel 4: embedding_avg EMA + normalized new_embedding (one float4/thread)
// ---------------------------------------------------------------------------
__global__ __launch_bounds__(256)
void emb_kernel(const float* __restrict__ avg_in, const float* __restrict__ embsum,
                const float* __restrict__ cs_ws,
                float* __restrict__ nemb_out, float* __restrict__ navg_out) {
    const float DECAY = 0.99f, OMD = 0.01f;
    int id = blockIdx.x * 256 + threadIdx.x;   // float4 index, K*D/4 total
    int k = id >> 6;                           // 64 float4 per code row
    float4 s = ld4(embsum + (size_t)id * 4);
    float4 a = ld4(avg_in + (size_t)id * 4);
    float4 na;
    na.x = a.x * DECAY + s.x * OMD;
    na.y = a.y * DECAY + s.y * OMD;
    na.z = a.z * DECAY + s.z * OMD;
    na.w = a.w * DECAY + s.w * OMD;
    st4(navg_out + (size_t)id * 4, na);
    float c = cs_ws[k];
    float4 ne;
    ne.x = na.x / c; ne.y = na.y / c; ne.z = na.z / c; ne.w = na.w / c;
    st4(nemb_out + (size_t)id * 4, ne);
}

// ---------------------------------------------------------------------------
// Kernel 5: final loss reduction (deterministic, one block)
// ---------------------------------------------------------------------------
__global__ __launch_bounds__(256)
void loss_kernel(const float* __restrict__ partials, int n,
                 float* __restrict__ out, float scale) {
    double s = 0.0;
    for (int i = threadIdx.x; i < n; i += 256) s += (double)partials[i];
    #pragma unroll
    for (int off = 32; off; off >>= 1) s += __shfl_down(s, off);
    __shared__ double red[4];
    int lane = threadIdx.x & 63, wid = threadIdx.x >> 6;
    if (lane == 0) red[wid] = s;
    __syncthreads();
    if (threadIdx.x == 0)
        out[0] = (float)((red[0] + red[1] + red[2] + red[3]) * (double)scale);
}

// ---------------------------------------------------------------------------
extern "C" void kernel_launch(void* const* d_in, const int* in_sizes, int n_in,
                              void* d_out, int out_size, void* d_ws, size_t ws_size,
                              hipStream_t stream) {
    const float* x    = (const float*)d_in[0];   // [N, 256]
    const float* emb  = (const float*)d_in[1];   // [1024, 256]
    const float* csz  = (const float*)d_in[2];   // [1024]
    const float* eavg = (const float*)d_in[3];   // [1024, 256]
    const int D = D_DIM, K = K_CODES;
    const int N = in_sizes[0] / D;

    float* out      = (float*)d_out;
    float* out_q    = out;                        // N*D  quantized_st
    float* out_loss = out_q + (size_t)N * D;      // 1    loss
    float* out_idx  = out_loss + 1;               // N    encoding_indices (as float)
    float* out_nemb = out_idx + N;                // K*D  new_embedding
    float* out_ncs  = out_nemb + (size_t)K * D;   // K    new_cluster_size
    float* out_navg = out_ncs + K;                // K*D  new_embedding_avg

    char* wsp = (char*)d_ws;
    int*   ws_idx    = (int*)wsp;    wsp += sizeof(int) * (size_t)N;
    float* ws_enorm  = (float*)wsp;  wsp += sizeof(float) * K;
    float* ws_counts = (float*)wsp;  wsp += sizeof(float) * K;
    float* ws_cs     = (float*)wsp;  wsp += sizeof(float) * K;
    float* ws_embsum = (float*)wsp;  wsp += sizeof(float) * (size_t)K * D;
    float* ws_part   = (float*)wsp;  // 2048 floats

    hipMemsetAsync(ws_counts, 0, sizeof(float) * K, stream);
    hipMemsetAsync(ws_embsum, 0, sizeof(float) * (size_t)K * D, stream);

    enorm_kernel<<<K / 4, 256, 0, stream>>>(emb, ws_enorm);
    argmin_kernel<<<N / 128, 256, 0, stream>>>(x, emb, ws_enorm, ws_idx, out_idx);

    const int SBLK = 2048;
    int rows_per_wave = (N + SBLK * 4 - 1) / (SBLK * 4);
    quant_scatter_kernel<<<SBLK, 256, 0, stream>>>(x, emb, ws_idx, out_q, ws_embsum,
                                                   ws_counts, ws_part, rows_per_wave, N);
    cs_kernel<<<1, 1024, 0, stream>>>(csz, ws_counts, out_ncs, ws_cs, K);
    emb_kernel<<<(K * D / 4) / 256, 256, 0, stream>>>(eavg, ws_embsum, ws_cs,
                                                      out_nemb, out_navg);
    loss_kernel<<<1, 256, 0, stream>>>(ws_part, SBLK, out_loss,
                                       1.0f / ((float)N * (float)D));
}

// Round 2
// 1041.490 us; speedup vs baseline: 1.7377x; 1.7377x over previous
//
#include <hip/hip_runtime.h>

#define D_DIM 256
#define K_CODES 1024
#define BM 128          // rows per block tile
#define BN 256          // codes per ct chunk
#define NCT (K_CODES / BN)   // 4
#define DT 32           // dims per staged chunk
#define NDT (D_DIM / DT)     // 8

typedef short bf16x8 __attribute__((ext_vector_type(8)));   // 8 bf16 = 4 VGPRs
typedef float f32x4  __attribute__((ext_vector_type(4)));

__device__ __forceinline__ const float4& ld4(const float* p) {
    return *reinterpret_cast<const float4*>(p);
}
__device__ __forceinline__ void st4(float* p, const float4& v) {
    *reinterpret_cast<float4*>(p) = v;
}
// round-to-nearest-even fp32 -> bf16 (as ushort)
__device__ __forceinline__ unsigned short f2bf(float f) {
    union { float f; unsigned u; } c{f};
    unsigned r = c.u + 0x7FFFu + ((c.u >> 16) & 1u);
    return (unsigned short)(r >> 16);
}
__device__ __forceinline__ float bf2f(unsigned short h) {
    union { unsigned u; float f; } c{(unsigned)h << 16};
    return c.f;
}

// ---------------------------------------------------------------------------
// Kernel 0: split emb into bf16 hi/lo + fp32 norms. One wave per code.
// ---------------------------------------------------------------------------
__global__ __launch_bounds__(256)
void splitnorm_kernel(const float* __restrict__ emb, unsigned short* __restrict__ ehi,
                      unsigned short* __restrict__ elo, float* __restrict__ enorm) {
    int gid = blockIdx.x * blockDim.x + threadIdx.x;
    int k = gid >> 6, lane = gid & 63;
    if (k >= K_CODES) return;
    float4 v = ld4(emb + (size_t)k * D_DIM + lane * 4);
    float nv = v.x * v.x + v.y * v.y + v.z * v.z + v.w * v.w;
    unsigned short h[4], l[4];
    float vv[4] = {v.x, v.y, v.z, v.w};
    #pragma unroll
    for (int j = 0; j < 4; ++j) {
        h[j] = f2bf(vv[j]);
        l[j] = f2bf(vv[j] - bf2f(h[j]));
    }
    uint2 hp, lp;
    hp.x = (unsigned)h[0] | ((unsigned)h[1] << 16);
    hp.y = (unsigned)h[2] | ((unsigned)h[3] << 16);
    lp.x = (unsigned)l[0] | ((unsigned)l[1] << 16);
    lp.y = (unsigned)l[2] | ((unsigned)l[3] << 16);
    *(uint2*)(ehi + (size_t)k * D_DIM + lane * 4) = hp;
    *(uint2*)(elo + (size_t)k * D_DIM + lane * 4) = lp;
    #pragma unroll
    for (int off = 32; off; off >>= 1) nv += __shfl_down(nv, off);
    if (lane == 0) enorm[k] = nv;
}

// ---------------------------------------------------------------------------
// Kernel 1: MFMA distance + argmin. 256 threads = 4 waves (2x2 wave grid),
// wave tile 64 rows x 128 cols. dist = ||e||^2 - 2*x.e via 3-term bf16 split.
// LDS layout [kgroup][row][8] -> each 16-lane group reads contiguous 256B.
// ---------------------------------------------------------------------------
__global__ __launch_bounds__(256, 2)
void argmin_mfma(const float* __restrict__ x,
                 const unsigned short* __restrict__ ehi,
                 const unsigned short* __restrict__ elo,
                 const float* __restrict__ enorm,
                 int* __restrict__ idx_out, float* __restrict__ idxf_out,
                 int* __restrict__ cnt) {
    __shared__ __align__(16) unsigned short xh_s[4][BM][8];
    __shared__ __align__(16) unsigned short xl_s[4][BM][8];
    __shared__ __align__(16) unsigned short eh_s[4][BN][8];
    __shared__ __align__(16) unsigned short el_s[4][BN][8];
    __shared__ __align__(16) float enorm_s[K_CODES];
    __shared__ float bestv_s[2][BM];
    __shared__ int   besti_s[2][BM];

    const int t = threadIdx.x;
    const int lane = t & 63;
    const int w = t >> 6;
    const int wr = w >> 1, wc = w & 1;
    const int RB = wr * 64, CB = wc * 128;
    const int l15 = lane & 15, l4 = lane >> 4;
    const long rowbase = (long)blockIdx.x * BM;

    // stage enorm once (read under the first barrier below)
    *(float4*)&enorm_s[t * 4] = ld4(enorm + t * 4);

    float bestv[4][4];
    int   besti[4][4];
    #pragma unroll
    for (int i = 0; i < 4; ++i)
        #pragma unroll
        for (int j = 0; j < 4; ++j) { bestv[i][j] = 3.4e38f; besti[i][j] = 0; }

    #pragma unroll 1
    for (int ct = 0; ct < NCT; ++ct) {
        f32x4 acc[4][8];
        #pragma unroll
        for (int ri = 0; ri < 4; ++ri)
            #pragma unroll
            for (int cj = 0; cj < 8; ++cj) acc[ri][cj] = (f32x4){0.f, 0.f, 0.f, 0.f};

        #pragma unroll 1
        for (int dt = 0; dt < NDT; ++dt) {
            __syncthreads();   // previous readers done (also covers enorm_s staging)
            // --- stage x tile (128 rows x 32 dims) fp32 -> bf16 hi/lo ---
            #pragma unroll
            for (int q = 0; q < 4; ++q) {
                int f = q * 256 + t;
                int r = f >> 3, c4 = f & 7;
                float4 v = ld4(x + (rowbase + r) * D_DIM + dt * DT + c4 * 4);
                int g = c4 >> 1, p = (c4 & 1) * 4;
                float vv[4] = {v.x, v.y, v.z, v.w};
                unsigned short h[4], l[4];
                #pragma unroll
                for (int j = 0; j < 4; ++j) {
                    h[j] = f2bf(vv[j]);
                    l[j] = f2bf(vv[j] - bf2f(h[j]));
                }
                uint2 hp, lp;
                hp.x = (unsigned)h[0] | ((unsigned)h[1] << 16);
                hp.y = (unsigned)h[2] | ((unsigned)h[3] << 16);
                lp.x = (unsigned)l[0] | ((unsigned)l[1] << 16);
                lp.y = (unsigned)l[2] | ((unsigned)l[3] << 16);
                *(uint2*)&xh_s[g][r][p] = hp;
                *(uint2*)&xl_s[g][r][p] = lp;
            }
            // --- stage e tile (256 codes x 32 dims) bf16 hi/lo (16B chunks) ---
            #pragma unroll
            for (int q = 0; q < 4; ++q) {
                int ch = q * 256 + t;
                int c = ch >> 2, qq = ch & 3;
                size_t gofs = ((size_t)(ct * BN + c)) * D_DIM + dt * DT + qq * 8;
                *(uint4*)&eh_s[qq][c][0] = *(const uint4*)(ehi + gofs);
                *(uint4*)&el_s[qq][c][0] = *(const uint4*)(elo + gofs);
            }
            __syncthreads();
            // --- fragments + MFMA ---
            bf16x8 ah[4], al[4];
            #pragma unroll
            for (int ri = 0; ri < 4; ++ri) {
                ah[ri] = *(const bf16x8*)&xh_s[l4][RB + ri * 16 + l15][0];
                al[ri] = *(const bf16x8*)&xl_s[l4][RB + ri * 16 + l15][0];
            }
            #pragma unroll
            for (int cj = 0; cj < 8; ++cj) {
                bf16x8 bh = *(const bf16x8*)&eh_s[l4][CB + cj * 16 + l15][0];
                bf16x8 bl = *(const bf16x8*)&el_s[l4][CB + cj * 16 + l15][0];
                #pragma unroll
                for (int ri = 0; ri < 4; ++ri) {
                    acc[ri][cj] = __builtin_amdgcn_mfma_f32_16x16x32_bf16(ah[ri], bh, acc[ri][cj], 0, 0, 0);
                    acc[ri][cj] = __builtin_amdgcn_mfma_f32_16x16x32_bf16(ah[ri], bl, acc[ri][cj], 0, 0, 0);
                    acc[ri][cj] = __builtin_amdgcn_mfma_f32_16x16x32_bf16(al[ri], bh, acc[ri][cj], 0, 0, 0);
                }
            }
        }
        // --- fold this 256-code chunk into running (min, argmin) ---
        #pragma unroll
        for (int cj = 0; cj < 8; ++cj) {
            int c = ct * BN + CB + cj * 16 + l15;
            float en = enorm_s[c];
            #pragma unroll
            for (int ri = 0; ri < 4; ++ri)
                #pragma unroll
                for (int r = 0; r < 4; ++r) {
                    float dist = fmaf(-2.0f, acc[ri][cj][r], en);
                    if (dist < bestv[ri][r]) { bestv[ri][r] = dist; besti[ri][r] = c; }
                }
        }
    }

    // butterfly across the 16 lanes (l15) sharing each row
    #pragma unroll
    for (int ri = 0; ri < 4; ++ri)
        #pragma unroll
        for (int r = 0; r < 4; ++r) {
            float bv = bestv[ri][r];
            int bi = besti[ri][r];
            #pragma unroll
            for (int off = 1; off < 16; off <<= 1) {
                float ov = __shfl_xor(bv, off);
                int oi = __shfl_xor(bi, off);
                if (ov < bv || (ov == bv && oi < bi)) { bv = ov; bi = oi; }
            }
            if (l15 == 0) {
                int row = RB + ri * 16 + l4 * 4 + r;
                bestv_s[wc][row] = bv;
                besti_s[wc][row] = bi;
            }
        }
    __syncthreads();
    if (t < BM) {
        float v0 = bestv_s[0][t], v1 = bestv_s[1][t];
        int i0 = besti_s[0][t], i1 = besti_s[1][t];
        int bi = (v1 < v0 || (v1 == v0 && i1 < i0)) ? i1 : i0;
        long row = rowbase + t;
        idx_out[row] = bi;
        idxf_out[row] = (float)bi;
        atomicAdd(&cnt[bi], 1);
    }
}

// ---------------------------------------------------------------------------
// Kernel 2: exclusive prefix sum over K=1024 counts -> offsets + cursor copy
// ---------------------------------------------------------------------------
__global__ __launch_bounds__(1024)
void prefix_kernel(const int* __restrict__ cnt, int* __restrict__ offs,
                   int* __restrict__ cursor) {
    int t = threadIdx.x;
    int v = cnt[t];
    int s = v;
    #pragma unroll
    for (int off = 1; off < 64; off <<= 1) {
        int u = __shfl_up(s, off);
        if ((t & 63) >= off) s += u;
    }
    __shared__ int wsum[16], woff[16];
    if ((t & 63) == 63) wsum[t >> 6] = s;
    __syncthreads();
    if (t < 16) {
        int a = 0;
        for (int i = 0; i < t; ++i) a += wsum[i];
        woff[t] = a;
    }
    __syncthreads();
    int excl = s - v + woff[t >> 6];
    offs[t] = excl;
    cursor[t] = excl;
}

// ---------------------------------------------------------------------------
// Kernel 3: bucket-fill row ids ordered by code
// ---------------------------------------------------------------------------
__global__ __launch_bounds__(256)
void fill_kernel(const int* __restrict__ idx, int* __restrict__ cursor,
                 int* __restrict__ order, int n) {
    int i = blockIdx.x * blockDim.x + threadIdx.x;
    if (i < n) {
        int k = idx[i];
        int pos = atomicAdd(&cursor[k], 1);
        order[pos] = i;
    }
}

// ---------------------------------------------------------------------------
// Kernel 4: per-code row sum (no atomics). One block per code.
// ---------------------------------------------------------------------------
__global__ __launch_bounds__(256)
void embsum_kernel(const float* __restrict__ x, const int* __restrict__ order,
                   const int* __restrict__ offs, const int* __restrict__ cnt,
                   float* __restrict__ embsum) {
    int k = blockIdx.x;
    int start = offs[k], n = cnt[k];
    int lane = threadIdx.x & 63, w = threadIdx.x >> 6;
    float4 s = {0.f, 0.f, 0.f, 0.f};
    for (int i = w; i < n; i += 4) {
        int row = order[start + i];
        float4 v = ld4(x + (size_t)row * D_DIM + lane * 4);
        s.x += v.x; s.y += v.y; s.z += v.z; s.w += v.w;
    }
    __shared__ float4 part[4][64];
    part[w][lane] = s;
    __syncthreads();
    if (w == 0) {
        float4 a = part[0][lane], b = part[1][lane], c = part[2][lane], d = part[3][lane];
        s.x = a.x + b.x + c.x + d.x;
        s.y = a.y + b.y + c.y + d.y;
        s.z = a.z + b.z + c.z + d.z;
        s.w = a.w + b.w + c.w + d.w;
        st4(embsum + (size_t)k * D_DIM + lane * 4, s);
    }
}

// ---------------------------------------------------------------------------
// Kernel 5: gather quantized, STE output, loss partials (no atomics)
// ---------------------------------------------------------------------------
__global__ __launch_bounds__(256)
void quant_kernel(const float* __restrict__ x, const float* __restrict__ emb,
                  const int* __restrict__ idx, float* __restrict__ qst_out,
                  float* __restrict__ partials, int rows_per_wave, int nrows) {
    const int t = threadIdx.x;
    const int lane = t & 63;
    const int wid = t >> 6;
    const long gw = (long)blockIdx.x * 4 + wid;
    float lsum = 0.0f;
    for (int rr = 0; rr < rows_per_wave; ++rr) {
        long row = gw * rows_per_wave + rr;
        if (row >= nrows) break;
        int k = idx[row];
        float4 xv = ld4(x + row * D_DIM + lane * 4);
        float4 qv = ld4(emb + (size_t)k * D_DIM + lane * 4);
        float4 o;
        o.x = xv.x + (qv.x - xv.x);
        o.y = xv.y + (qv.y - xv.y);
        o.z = xv.z + (qv.z - xv.z);
        o.w = xv.w + (qv.w - xv.w);
        st4(qst_out + row * D_DIM + lane * 4, o);
        float dx = xv.x - qv.x, dy = xv.y - qv.y, dz = xv.z - qv.z, dw = xv.w - qv.w;
        lsum += dx * dx + dy * dy + dz * dz + dw * dw;
    }
    #pragma unroll
    for (int off = 32; off; off >>= 1) lsum += __shfl_down(lsum, off);
    __shared__ float wsum[4];
    if (lane == 0) wsum[wid] = lsum;
    __syncthreads();
    if (t == 0) partials[blockIdx.x] = wsum[0] + wsum[1] + wsum[2] + wsum[3];
}

// ---------------------------------------------------------------------------
// Kernel 6: cluster-size EMA + Laplace-smoothed denominator (one block)
// ---------------------------------------------------------------------------
__global__ __launch_bounds__(1024)
void cs_kernel(const float* __restrict__ cs_in, const int* __restrict__ counts,
               float* __restrict__ ncs_out, float* __restrict__ cs_ws, int K) {
    const float DECAY = 0.99f, OMD = 0.01f, EPSF = 1e-5f;
    int t = threadIdx.x;
    float ncs = 0.0f;
    if (t < K) {
        ncs = cs_in[t] * DECAY + (float)counts[t] * OMD;
        ncs_out[t] = ncs;
    }
    float s = ncs;
    #pragma unroll
    for (int off = 32; off; off >>= 1) s += __shfl_down(s, off);
    __shared__ float red[16];
    __shared__ float n_sh;
    if ((t & 63) == 0) red[t >> 6] = s;
    __syncthreads();
    if (t == 0) {
        float n = 0.0f;
        for (int i = 0; i < (int)(blockDim.x >> 6); ++i) n += red[i];
        n_sh = n;
    }
    __syncthreads();
    if (t < K) {
        float n = n_sh;
        cs_ws[t] = (ncs + EPSF) / (n + (float)K * EPSF) * n;
    }
}

// ---------------------------------------------------------------------------
// Kernel 7: embedding_avg EMA + normalized new_embedding
// ---------------------------------------------------------------------------
__global__ __launch_bounds__(256)
void emb_kernel(const float* __restrict__ avg_in, const float* __restrict__ embsum,
                const float* __restrict__ cs_ws,
                float* __restrict__ nemb_out, float* __restrict__ navg_out) {
    const float DECAY = 0.99f, OMD = 0.01f;
    int id = blockIdx.x * 256 + threadIdx.x;
    int k = id >> 6;
    float4 s = ld4(embsum + (size_t)id * 4);
    float4 a = ld4(avg_in + (size_t)id * 4);
    float4 na;
    na.x = a.x * DECAY + s.x * OMD;
    na.y = a.y * DECAY + s.y * OMD;
    na.z = a.z * DECAY + s.z * OMD;
    na.w = a.w * DECAY + s.w * OMD;
    st4(navg_out + (size_t)id * 4, na);
    float c = cs_ws[k];
    float4 ne;
    ne.x = na.x / c; ne.y = na.y / c; ne.z = na.z / c; ne.w = na.w / c;
    st4(nemb_out + (size_t)id * 4, ne);
}

// ---------------------------------------------------------------------------
// Kernel 8: final loss reduction (deterministic, one block)
// ---------------------------------------------------------------------------
__global__ __launch_bounds__(256)
void loss_kernel(const float* __restrict__ partials, int n,
                 float* __restrict__ out, float scale) {
    double s = 0.0;
    for (int i = threadIdx.x; i < n; i += 256) s += (double)partials[i];
    #pragma unroll
    for (int off = 32; off; off >>= 1) s += __shfl_down(s, off);
    __shared__ double red[4];
    int lane = threadIdx.x & 63, wid = threadIdx.x >> 6;
    if (lane == 0) red[wid] = s;
    __syncthreads();
    if (threadIdx.x == 0)
        out[0] = (float)((red[0] + red[1] + red[2] + red[3]) * (double)scale);
}

// ---------------------------------------------------------------------------
extern "C" void kernel_launch(void* const* d_in, const int* in_sizes, int n_in,
                              void* d_out, int out_size, void* d_ws, size_t ws_size,
                              hipStream_t stream) {
    const float* x    = (const float*)d_in[0];   // [N, 256]
    const float* emb  = (const float*)d_in[1];   // [1024, 256]
    const float* csz  = (const float*)d_in[2];   // [1024]
    const float* eavg = (const float*)d_in[3];   // [1024, 256]
    const int D = D_DIM, K = K_CODES;
    const int N = in_sizes[0] / D;

    float* out      = (float*)d_out;
    float* out_q    = out;                        // N*D  quantized_st
    float* out_loss = out_q + (size_t)N * D;      // 1    loss
    float* out_idx  = out_loss + 1;               // N    encoding_indices (as float)
    float* out_nemb = out_idx + N;                // K*D  new_embedding
    float* out_ncs  = out_nemb + (size_t)K * D;   // K    new_cluster_size
    float* out_navg = out_ncs + K;                // K*D  new_embedding_avg

    char* wsp = (char*)d_ws;
    int*   ws_idx    = (int*)wsp;            wsp += sizeof(int) * (size_t)N;
    int*   ws_order  = (int*)wsp;            wsp += sizeof(int) * (size_t)N;
    float* ws_enorm  = (float*)wsp;          wsp += sizeof(float) * K;
    int*   ws_cnt    = (int*)wsp;            wsp += sizeof(int) * K;
    int*   ws_offs   = (int*)wsp;            wsp += sizeof(int) * K;
    int*   ws_cursor = (int*)wsp;            wsp += sizeof(int) * K;
    float* ws_cs     = (float*)wsp;          wsp += sizeof(float) * K;
    float* ws_embsum = (float*)wsp;          wsp += sizeof(float) * (size_t)K * D;
    unsigned short* ws_ehi = (unsigned short*)wsp;  wsp += sizeof(unsigned short) * (size_t)K * D;
    unsigned short* ws_elo = (unsigned short*)wsp;  wsp += sizeof(unsigned short) * (size_t)K * D;
    float* ws_part   = (float*)wsp;          // 2048 floats

    hipMemsetAsync(ws_cnt, 0, sizeof(int) * K, stream);

    splitnorm_kernel<<<K / 4, 256, 0, stream>>>(emb, ws_ehi, ws_elo, ws_enorm);
    argmin_mfma<<<N / BM, 256, 0, stream>>>(x, ws_ehi, ws_elo, ws_enorm,
                                            ws_idx, out_idx, ws_cnt);
    prefix_kernel<<<1, 1024, 0, stream>>>(ws_cnt, ws_offs, ws_cursor);
    fill_kernel<<<(N + 255) / 256, 256, 0, stream>>>(ws_idx, ws_cursor, ws_order, N);
    embsum_kernel<<<K, 256, 0, stream>>>(x, ws_order, ws_offs, ws_cnt, ws_embsum);

    const int QBLK = 2048;
    int rows_per_wave = (N + QBLK * 4 - 1) / (QBLK * 4);
    quant_kernel<<<QBLK, 256, 0, stream>>>(x, emb, ws_idx, out_q, ws_part,
                                           rows_per_wave, N);
    cs_kernel<<<1, 1024, 0, stream>>>(csz, ws_cnt, out_ncs, ws_cs, K);
    emb_kernel<<<(K * D / 4) / 256, 256, 0, stream>>>(eavg, ws_embsum, ws_cs,
                                                      out_nemb, out_navg);
    loss_kernel<<<1, 256, 0, stream>>>(ws_part, QBLK, out_loss,
                                       1.0f / ((float)N * (float)D));
}

// Round 3
// 546.405 us; speedup vs baseline: 3.3122x; 1.9061x over previous
//
#include <hip/hip_runtime.h>

#define D_DIM 256
#define K_CODES 1024
#define BM 128          // rows per block tile
#define BN 256          // codes per ct chunk
#define NCT (K_CODES / BN)   // 4
#define DT 32           // dims per staged chunk
#define NDT (D_DIM / DT)     // 8
#define CH 64           // rows per chunk block (fused embsum/quant)

typedef short bf16x8 __attribute__((ext_vector_type(8)));   // 8 bf16 = 4 VGPRs
typedef float f32x4  __attribute__((ext_vector_type(4)));

__device__ __forceinline__ const float4& ld4(const float* p) {
    return *reinterpret_cast<const float4*>(p);
}
__device__ __forceinline__ void st4(float* p, const float4& v) {
    *reinterpret_cast<float4*>(p) = v;
}
// round-to-nearest-even fp32 -> bf16 (as ushort)
__device__ __forceinline__ unsigned short f2bf(float f) {
    union { float f; unsigned u; } c{f};
    unsigned r = c.u + 0x7FFFu + ((c.u >> 16) & 1u);
    return (unsigned short)(r >> 16);
}
__device__ __forceinline__ float bf2f(unsigned short h) {
    union { unsigned u; float f; } c{(unsigned)h << 16};
    return c.f;
}
__device__ __forceinline__ void split4(const float4& v, uint2& hp, uint2& lp) {
    float vv[4] = {v.x, v.y, v.z, v.w};
    unsigned short h[4], l[4];
    #pragma unroll
    for (int j = 0; j < 4; ++j) {
        h[j] = f2bf(vv[j]);
        l[j] = f2bf(vv[j] - bf2f(h[j]));
    }
    hp.x = (unsigned)h[0] | ((unsigned)h[1] << 16);
    hp.y = (unsigned)h[2] | ((unsigned)h[3] << 16);
    lp.x = (unsigned)l[0] | ((unsigned)l[1] << 16);
    lp.y = (unsigned)l[2] | ((unsigned)l[3] << 16);
}

// ---------------------------------------------------------------------------
// Kernel 0: split emb into bf16 hi/lo + fp32 norms. One wave per code.
// ---------------------------------------------------------------------------
__global__ __launch_bounds__(256)
void splitnorm_kernel(const float* __restrict__ emb, unsigned short* __restrict__ ehi,
                      unsigned short* __restrict__ elo, float* __restrict__ enorm) {
    int gid = blockIdx.x * blockDim.x + threadIdx.x;
    int k = gid >> 6, lane = gid & 63;
    if (k >= K_CODES) return;
    float4 v = ld4(emb + (size_t)k * D_DIM + lane * 4);
    float nv = v.x * v.x + v.y * v.y + v.z * v.z + v.w * v.w;
    uint2 hp, lp;
    split4(v, hp, lp);
    *(uint2*)(ehi + (size_t)k * D_DIM + lane * 4) = hp;
    *(uint2*)(elo + (size_t)k * D_DIM + lane * 4) = lp;
    #pragma unroll
    for (int off = 32; off; off >>= 1) nv += __shfl_down(nv, off);
    if (lane == 0) enorm[k] = nv;
}

// ---------------------------------------------------------------------------
// Kernel 0b: split x into bf16 hi/lo (streaming, grid-stride)
// ---------------------------------------------------------------------------
__global__ __launch_bounds__(256)
void xsplit_kernel(const float* __restrict__ x, unsigned short* __restrict__ xhi,
                   unsigned short* __restrict__ xlo, long n4) {
    long stride = (long)gridDim.x * 256;
    for (long i = (long)blockIdx.x * 256 + threadIdx.x; i < n4; i += stride) {
        float4 v = ld4(x + i * 4);
        uint2 hp, lp;
        split4(v, hp, lp);
        *(uint2*)(xhi + i * 4) = hp;
        *(uint2*)(xlo + i * 4) = lp;
    }
}

// ---------------------------------------------------------------------------
// Kernel 1: MFMA distance + argmin. 256 threads = 4 waves (2x2 wave grid),
// wave tile 64 rows x 128 cols. dist = ||e||^2 - 2*x.e via 3-term bf16 split.
// x pre-split -> staging is pure 16B copies (no conversion VALU in hot loop).
// ---------------------------------------------------------------------------
__global__ __launch_bounds__(256, 2)
void argmin_mfma(const unsigned short* __restrict__ xhi,
                 const unsigned short* __restrict__ xlo,
                 const unsigned short* __restrict__ ehi,
                 const unsigned short* __restrict__ elo,
                 const float* __restrict__ enorm,
                 int* __restrict__ idx_out, float* __restrict__ idxf_out,
                 int* __restrict__ cnt) {
    __shared__ __align__(16) unsigned short xh_s[4][BM][8];
    __shared__ __align__(16) unsigned short xl_s[4][BM][8];
    __shared__ __align__(16) unsigned short eh_s[4][BN][8];
    __shared__ __align__(16) unsigned short el_s[4][BN][8];
    __shared__ __align__(16) float enorm_s[K_CODES];
    __shared__ float bestv_s[2][BM];
    __shared__ int   besti_s[2][BM];

    const int t = threadIdx.x;
    const int lane = t & 63;
    const int w = t >> 6;
    const int wr = w >> 1, wc = w & 1;
    const int RB = wr * 64, CB = wc * 128;
    const int l15 = lane & 15, l4 = lane >> 4;
    const long rowbase = (long)blockIdx.x * BM;

    *(float4*)&enorm_s[t * 4] = ld4(enorm + t * 4);

    float bestv[4][4];
    int   besti[4][4];
    #pragma unroll
    for (int i = 0; i < 4; ++i)
        #pragma unroll
        for (int j = 0; j < 4; ++j) { bestv[i][j] = 3.4e38f; besti[i][j] = 0; }

    #pragma unroll 1
    for (int ct = 0; ct < NCT; ++ct) {
        f32x4 acc[4][8];
        #pragma unroll
        for (int ri = 0; ri < 4; ++ri)
            #pragma unroll
            for (int cj = 0; cj < 8; ++cj) acc[ri][cj] = (f32x4){0.f, 0.f, 0.f, 0.f};

        #pragma unroll 1
        for (int dt = 0; dt < NDT; ++dt) {
            __syncthreads();   // previous readers done (also covers enorm_s staging)
            // --- stage x tile (128 rows x 32 dims) hi/lo, 16B chunks ---
            #pragma unroll
            for (int q = 0; q < 2; ++q) {
                int f = q * 256 + t;           // 512 chunks per array
                int r = f >> 2, qq = f & 3;
                size_t g = (size_t)(rowbase + r) * D_DIM + dt * DT + qq * 8;
                *(uint4*)&xh_s[qq][r][0] = *(const uint4*)(xhi + g);
                *(uint4*)&xl_s[qq][r][0] = *(const uint4*)(xlo + g);
            }
            // --- stage e tile (256 codes x 32 dims) hi/lo, 16B chunks ---
            #pragma unroll
            for (int q = 0; q < 4; ++q) {
                int ch = q * 256 + t;
                int c = ch >> 2, qq = ch & 3;
                size_t gofs = ((size_t)(ct * BN + c)) * D_DIM + dt * DT + qq * 8;
                *(uint4*)&eh_s[qq][c][0] = *(const uint4*)(ehi + gofs);
                *(uint4*)&el_s[qq][c][0] = *(const uint4*)(elo + gofs);
            }
            __syncthreads();
            // --- fragments + MFMA ---
            bf16x8 ah[4], al[4];
            #pragma unroll
            for (int ri = 0; ri < 4; ++ri) {
                ah[ri] = *(const bf16x8*)&xh_s[l4][RB + ri * 16 + l15][0];
                al[ri] = *(const bf16x8*)&xl_s[l4][RB + ri * 16 + l15][0];
            }
            #pragma unroll
            for (int cj = 0; cj < 8; ++cj) {
                bf16x8 bh = *(const bf16x8*)&eh_s[l4][CB + cj * 16 + l15][0];
                bf16x8 bl = *(const bf16x8*)&el_s[l4][CB + cj * 16 + l15][0];
                #pragma unroll
                for (int ri = 0; ri < 4; ++ri) {
                    acc[ri][cj] = __builtin_amdgcn_mfma_f32_16x16x32_bf16(ah[ri], bh, acc[ri][cj], 0, 0, 0);
                    acc[ri][cj] = __builtin_amdgcn_mfma_f32_16x16x32_bf16(ah[ri], bl, acc[ri][cj], 0, 0, 0);
                    acc[ri][cj] = __builtin_amdgcn_mfma_f32_16x16x32_bf16(al[ri], bh, acc[ri][cj], 0, 0, 0);
                }
            }
        }
        // --- fold this 256-code chunk into running (min, argmin) ---
        #pragma unroll
        for (int cj = 0; cj < 8; ++cj) {
            int c = ct * BN + CB + cj * 16 + l15;
            float en = enorm_s[c];
            #pragma unroll
            for (int ri = 0; ri < 4; ++ri)
                #pragma unroll
                for (int r = 0; r < 4; ++r) {
                    float dist = fmaf(-2.0f, acc[ri][cj][r], en);
                    if (dist < bestv[ri][r]) { bestv[ri][r] = dist; besti[ri][r] = c; }
                }
        }
    }

    // butterfly across the 16 lanes (l15) sharing each row
    #pragma unroll
    for (int ri = 0; ri < 4; ++ri)
        #pragma unroll
        for (int r = 0; r < 4; ++r) {
            float bv = bestv[ri][r];
            int bi = besti[ri][r];
            #pragma unroll
            for (int off = 1; off < 16; off <<= 1) {
                float ov = __shfl_xor(bv, off);
                int oi = __shfl_xor(bi, off);
                if (ov < bv || (ov == bv && oi < bi)) { bv = ov; bi = oi; }
            }
            if (l15 == 0) {
                int row = RB + ri * 16 + l4 * 4 + r;
                bestv_s[wc][row] = bv;
                besti_s[wc][row] = bi;
            }
        }
    __syncthreads();
    if (t < BM) {
        float v0 = bestv_s[0][t], v1 = bestv_s[1][t];
        int i0 = besti_s[0][t], i1 = besti_s[1][t];
        int bi = (v1 < v0 || (v1 == v0 && i1 < i0)) ? i1 : i0;
        long row = rowbase + t;
        idx_out[row] = bi;
        idxf_out[row] = (float)bi;
        atomicAdd(&cnt[bi], 1);
    }
}

// ---------------------------------------------------------------------------
// Kernel 2: exclusive prefix sum over K=1024 counts -> offsets + cursor copy
// ---------------------------------------------------------------------------
__global__ __launch_bounds__(1024)
void prefix_kernel(const int* __restrict__ cnt, int* __restrict__ offs,
                   int* __restrict__ cursor) {
    int t = threadIdx.x;
    int v = cnt[t];
    int s = v;
    #pragma unroll
    for (int off = 1; off < 64; off <<= 1) {
        int u = __shfl_up(s, off);
        if ((t & 63) >= off) s += u;
    }
    __shared__ int wsum[16], woff[16];
    if ((t & 63) == 63) wsum[t >> 6] = s;
    __syncthreads();
    if (t < 16) {
        int a = 0;
        for (int i = 0; i < t; ++i) a += wsum[i];
        woff[t] = a;
    }
    __syncthreads();
    int excl = s - v + woff[t >> 6];
    offs[t] = excl;
    cursor[t] = excl;
}

// ---------------------------------------------------------------------------
// Kernel 3: bucket-fill row ids (and their code) ordered by code
// ---------------------------------------------------------------------------
__global__ __launch_bounds__(256)
void fill_kernel(const int* __restrict__ idx, int* __restrict__ cursor,
                 int* __restrict__ order, int* __restrict__ key, int n) {
    int i = blockIdx.x * blockDim.x + threadIdx.x;
    if (i < n) {
        int k = idx[i];
        int pos = atomicAdd(&cursor[k], 1);
        order[pos] = i;
        key[pos] = k;
    }
}

// ---------------------------------------------------------------------------
// Kernel 4: fused per-chunk embsum (segment flush) + quantized STE + loss.
// 64 code-sorted rows per block; load-balanced regardless of cluster skew.
// ---------------------------------------------------------------------------
__global__ __launch_bounds__(256)
void chunk_kernel(const float* __restrict__ x, const float* __restrict__ emb,
                  const int* __restrict__ order, const int* __restrict__ key,
                  float* __restrict__ qst_out, float* __restrict__ embsum,
                  float* __restrict__ partials, int n) {
    const int t = threadIdx.x;
    const int lane = t & 63;
    const int w = t >> 6;
    const long base = (long)blockIdx.x * CH;
    float lsum = 0.0f;
    int cur_k = -1;
    float4 s = {0.f, 0.f, 0.f, 0.f};
    for (int i = w; i < CH; i += 4) {
        long pos = base + i;
        if (pos >= n) break;
        int row = order[pos];
        int k = key[pos];
        float4 xv = ld4(x + (size_t)row * D_DIM + lane * 4);
        float4 qv = ld4(emb + (size_t)k * D_DIM + lane * 4);
        if (k != cur_k) {
            if (cur_k >= 0) {
                float* p = embsum + (size_t)cur_k * D_DIM + lane * 4;
                atomicAdd(p + 0, s.x); atomicAdd(p + 1, s.y);
                atomicAdd(p + 2, s.z); atomicAdd(p + 3, s.w);
            }
            s = {0.f, 0.f, 0.f, 0.f};
            cur_k = k;
        }
        s.x += xv.x; s.y += xv.y; s.z += xv.z; s.w += xv.w;
        float4 o;   // x + (q - x), exactly as the reference computes the STE
        o.x = xv.x + (qv.x - xv.x);
        o.y = xv.y + (qv.y - xv.y);
        o.z = xv.z + (qv.z - xv.z);
        o.w = xv.w + (qv.w - xv.w);
        st4(qst_out + (size_t)row * D_DIM + lane * 4, o);
        float dx = xv.x - qv.x, dy = xv.y - qv.y, dz = xv.z - qv.z, dw = xv.w - qv.w;
        lsum += dx * dx + dy * dy + dz * dz + dw * dw;
    }
    if (cur_k >= 0) {
        float* p = embsum + (size_t)cur_k * D_DIM + lane * 4;
        atomicAdd(p + 0, s.x); atomicAdd(p + 1, s.y);
        atomicAdd(p + 2, s.z); atomicAdd(p + 3, s.w);
    }
    #pragma unroll
    for (int off = 32; off; off >>= 1) lsum += __shfl_down(lsum, off);
    __shared__ float wsum[4];
    if (lane == 0) wsum[w] = lsum;
    __syncthreads();
    if (t == 0) partials[blockIdx.x] = wsum[0] + wsum[1] + wsum[2] + wsum[3];
}

// ---------------------------------------------------------------------------
// Kernel 5: cluster-size EMA + Laplace-smoothed denominator (one block)
// ---------------------------------------------------------------------------
__global__ __launch_bounds__(1024)
void cs_kernel(const float* __restrict__ cs_in, const int* __restrict__ counts,
               float* __restrict__ ncs_out, float* __restrict__ cs_ws, int K) {
    const float DECAY = 0.99f, OMD = 0.01f, EPSF = 1e-5f;
    int t = threadIdx.x;
    float ncs = 0.0f;
    if (t < K) {
        ncs = cs_in[t] * DECAY + (float)counts[t] * OMD;
        ncs_out[t] = ncs;
    }
    float s = ncs;
    #pragma unroll
    for (int off = 32; off; off >>= 1) s += __shfl_down(s, off);
    __shared__ float red[16];
    __shared__ float n_sh;
    if ((t & 63) == 0) red[t >> 6] = s;
    __syncthreads();
    if (t == 0) {
        float n = 0.0f;
        for (int i = 0; i < (int)(blockDim.x >> 6); ++i) n += red[i];
        n_sh = n;
    }
    __syncthreads();
    if (t < K) {
        float n = n_sh;
        cs_ws[t] = (ncs + EPSF) / (n + (float)K * EPSF) * n;
    }
}

// ---------------------------------------------------------------------------
// Kernel 6: embedding_avg EMA + normalized new_embedding
// ---------------------------------------------------------------------------
__global__ __launch_bounds__(256)
void emb_kernel(const float* __restrict__ avg_in, const float* __restrict__ embsum,
                const float* __restrict__ cs_ws,
                float* __restrict__ nemb_out, float* __restrict__ navg_out) {
    const float DECAY = 0.99f, OMD = 0.01f;
    int id = blockIdx.x * 256 + threadIdx.x;
    int k = id >> 6;
    float4 s = ld4(embsum + (size_t)id * 4);
    float4 a = ld4(avg_in + (size_t)id * 4);
    float4 na;
    na.x = a.x * DECAY + s.x * OMD;
    na.y = a.y * DECAY + s.y * OMD;
    na.z = a.z * DECAY + s.z * OMD;
    na.w = a.w * DECAY + s.w * OMD;
    st4(navg_out + (size_t)id * 4, na);
    float c = cs_ws[k];
    float4 ne;
    ne.x = na.x / c; ne.y = na.y / c; ne.z = na.z / c; ne.w = na.w / c;
    st4(nemb_out + (size_t)id * 4, ne);
}

// ---------------------------------------------------------------------------
// Kernel 7: final loss reduction (deterministic, one block)
// ---------------------------------------------------------------------------
__global__ __launch_bounds__(256)
void loss_kernel(const float* __restrict__ partials, int n,
                 float* __restrict__ out, float scale) {
    double s = 0.0;
    for (int i = threadIdx.x; i < n; i += 256) s += (double)partials[i];
    #pragma unroll
    for (int off = 32; off; off >>= 1) s += __shfl_down(s, off);
    __shared__ double red[4];
    int lane = threadIdx.x & 63, wid = threadIdx.x >> 6;
    if (lane == 0) red[wid] = s;
    __syncthreads();
    if (threadIdx.x == 0)
        out[0] = (float)((red[0] + red[1] + red[2] + red[3]) * (double)scale);
}

// ---------------------------------------------------------------------------
extern "C" void kernel_launch(void* const* d_in, const int* in_sizes, int n_in,
                              void* d_out, int out_size, void* d_ws, size_t ws_size,
                              hipStream_t stream) {
    const float* x    = (const float*)d_in[0];   // [N, 256]
    const float* emb  = (const float*)d_in[1];   // [1024, 256]
    const float* csz  = (const float*)d_in[2];   // [1024]
    const float* eavg = (const float*)d_in[3];   // [1024, 256]
    const int D = D_DIM, K = K_CODES;
    const int N = in_sizes[0] / D;

    float* out      = (float*)d_out;
    float* out_q    = out;                        // N*D  quantized_st
    float* out_loss = out_q + (size_t)N * D;      // 1    loss
    float* out_idx  = out_loss + 1;               // N    encoding_indices (as float)
    float* out_nemb = out_idx + N;                // K*D  new_embedding
    float* out_ncs  = out_nemb + (size_t)K * D;   // K    new_cluster_size
    float* out_navg = out_ncs + K;                // K*D  new_embedding_avg

    char* wsp = (char*)d_ws;
    int*   ws_idx    = (int*)wsp;            wsp += sizeof(int) * (size_t)N;
    int*   ws_order  = (int*)wsp;            wsp += sizeof(int) * (size_t)N;
    int*   ws_key    = (int*)wsp;            wsp += sizeof(int) * (size_t)N;
    float* ws_enorm  = (float*)wsp;          wsp += sizeof(float) * K;
    int*   ws_cnt    = (int*)wsp;            wsp += sizeof(int) * K;
    int*   ws_offs   = (int*)wsp;            wsp += sizeof(int) * K;
    int*   ws_cursor = (int*)wsp;            wsp += sizeof(int) * K;
    float* ws_cs     = (float*)wsp;          wsp += sizeof(float) * K;
    float* ws_embsum = (float*)wsp;          wsp += sizeof(float) * (size_t)K * D;
    unsigned short* ws_ehi = (unsigned short*)wsp;  wsp += sizeof(unsigned short) * (size_t)K * D;
    unsigned short* ws_elo = (unsigned short*)wsp;  wsp += sizeof(unsigned short) * (size_t)K * D;
    float* ws_part   = (float*)wsp;          // N/CH floats

    // x hi/lo scratch lives in the out_q region (overwritten later by chunk_kernel)
    unsigned short* ws_xhi = (unsigned short*)out_q;
    unsigned short* ws_xlo = ws_xhi + (size_t)N * D;

    hipMemsetAsync(ws_cnt, 0, sizeof(int) * K, stream);
    hipMemsetAsync(ws_embsum, 0, sizeof(float) * (size_t)K * D, stream);

    splitnorm_kernel<<<K / 4, 256, 0, stream>>>(emb, ws_ehi, ws_elo, ws_enorm);
    xsplit_kernel<<<2048, 256, 0, stream>>>(x, ws_xhi, ws_xlo, (long)N * D / 4);
    argmin_mfma<<<N / BM, 256, 0, stream>>>(ws_xhi, ws_xlo, ws_ehi, ws_elo, ws_enorm,
                                            ws_idx, out_idx, ws_cnt);
    prefix_kernel<<<1, 1024, 0, stream>>>(ws_cnt, ws_offs, ws_cursor);
    fill_kernel<<<(N + 255) / 256, 256, 0, stream>>>(ws_idx, ws_cursor, ws_order,
                                                     ws_key, N);
    const int NCHUNK = (N + CH - 1) / CH;   // 2048
    chunk_kernel<<<NCHUNK, 256, 0, stream>>>(x, emb, ws_order, ws_key, out_q,
                                             ws_embsum, ws_part, N);
    cs_kernel<<<1, 1024, 0, stream>>>(csz, ws_cnt, out_ncs, ws_cs, K);
    emb_kernel<<<(K * D / 4) / 256, 256, 0, stream>>>(eavg, ws_embsum, ws_cs,
                                                      out_nemb, out_navg);
    loss_kernel<<<1, 256, 0, stream>>>(ws_part, NCHUNK, out_loss,
                                       1.0f / ((float)N * (float)D));
}

// Round 4
// 531.144 us; speedup vs baseline: 3.4074x; 1.0287x over previous
//
#include <hip/hip_runtime.h>

#define D_DIM 256
#define K_CODES 1024
#define BM 128          // rows per block tile
#define BN 256          // codes per ct chunk
#define NCT (K_CODES / BN)   // 4
#define DT 32           // dims per staged chunk
#define NDT (D_DIM / DT)     // 8
#define CH 64           // rows per chunk block (fused embsum/quant)

typedef short bf16x8 __attribute__((ext_vector_type(8)));   // 8 bf16 = 4 VGPRs
typedef float f32x4  __attribute__((ext_vector_type(4)));

__device__ __forceinline__ const float4& ld4(const float* p) {
    return *reinterpret_cast<const float4*>(p);
}
__device__ __forceinline__ void st4(float* p, const float4& v) {
    *reinterpret_cast<float4*>(p) = v;
}
// round-to-nearest-even fp32 -> bf16 (as ushort)
__device__ __forceinline__ unsigned short f2bf(float f) {
    union { float f; unsigned u; } c{f};
    unsigned r = c.u + 0x7FFFu + ((c.u >> 16) & 1u);
    return (unsigned short)(r >> 16);
}
__device__ __forceinline__ float bf2f(unsigned short h) {
    union { unsigned u; float f; } c{(unsigned)h << 16};
    return c.f;
}
// 8 fp32 -> hi/lo bf16x8 fragments
__device__ __forceinline__ void cvt8(f32x4 a0, f32x4 a1, bf16x8& hi, bf16x8& lo) {
    #pragma unroll
    for (int j = 0; j < 4; ++j) {
        unsigned short h = f2bf(a0[j]);
        unsigned short l = f2bf(a0[j] - bf2f(h));
        hi[j] = (short)h; lo[j] = (short)l;
    }
    #pragma unroll
    for (int j = 0; j < 4; ++j) {
        unsigned short h = f2bf(a1[j]);
        unsigned short l = f2bf(a1[j] - bf2f(h));
        hi[4 + j] = (short)h; lo[4 + j] = (short)l;
    }
}
// async global->LDS, 16B per lane, wave-uniform LDS base
typedef __attribute__((address_space(3))) void lds_void;
typedef const __attribute__((address_space(1))) void glb_void;
__device__ __forceinline__ void load_lds16(const void* g, void* l) {
    __builtin_amdgcn_global_load_lds((glb_void*)g, (lds_void*)l, 16, 0, 0);
}

// ---------------------------------------------------------------------------
// Kernel 0: split emb into bf16 hi/lo + fp32 norms. One wave per code.
// ---------------------------------------------------------------------------
__global__ __launch_bounds__(256)
void splitnorm_kernel(const float* __restrict__ emb, unsigned short* __restrict__ ehi,
                      unsigned short* __restrict__ elo, float* __restrict__ enorm) {
    int gid = blockIdx.x * blockDim.x + threadIdx.x;
    int k = gid >> 6, lane = gid & 63;
    if (k >= K_CODES) return;
    float4 v = ld4(emb + (size_t)k * D_DIM + lane * 4);
    float nv = v.x * v.x + v.y * v.y + v.z * v.z + v.w * v.w;
    unsigned short h[4], l[4];
    float vv[4] = {v.x, v.y, v.z, v.w};
    #pragma unroll
    for (int j = 0; j < 4; ++j) {
        h[j] = f2bf(vv[j]);
        l[j] = f2bf(vv[j] - bf2f(h[j]));
    }
    uint2 hp, lp;
    hp.x = (unsigned)h[0] | ((unsigned)h[1] << 16);
    hp.y = (unsigned)h[2] | ((unsigned)h[3] << 16);
    lp.x = (unsigned)l[0] | ((unsigned)l[1] << 16);
    lp.y = (unsigned)l[2] | ((unsigned)l[3] << 16);
    *(uint2*)(ehi + (size_t)k * D_DIM + lane * 4) = hp;
    *(uint2*)(elo + (size_t)k * D_DIM + lane * 4) = lp;
    #pragma unroll
    for (int off = 32; off; off >>= 1) nv += __shfl_down(nv, off);
    if (lane == 0) enorm[k] = nv;
}

// ---------------------------------------------------------------------------
// Kernel 1: MFMA distance + argmin, pipelined (m97-style 2-phase).
// 4 waves (2x2), wave tile 64 rows x 128 cols; acc covers 256 cols per ct.
// global_load_lds staging, double-buffered; x kept fp32 in LDS, converted to
// bf16 hi/lo at fragment-read time. XOR source-swizzle vs bank conflicts.
// ---------------------------------------------------------------------------
__global__ __launch_bounds__(256, 1)
void argmin_mfma(const float* __restrict__ x,
                 const unsigned short* __restrict__ ehi,
                 const unsigned short* __restrict__ elo,
                 const float* __restrict__ enorm,
                 int* __restrict__ idx_out, float* __restrict__ idxf_out,
                 int* __restrict__ cnt) {
    // 96 KB of double-buffered tiles + 4 KB enorm + reduce scratch
    __shared__ __align__(16) float          xs[2][BM][DT];   // fp32 x tile
    __shared__ __align__(16) unsigned short ehs[2][BN][DT];  // bf16 hi
    __shared__ __align__(16) unsigned short els[2][BN][DT];  // bf16 lo
    __shared__ __align__(16) float enorm_s[K_CODES];
    __shared__ float bestv_s[2][BM];
    __shared__ int   besti_s[2][BM];

    const int t = threadIdx.x;
    const int lane = t & 63;
    const int w = t >> 6;
    const int wr = w >> 1, wc = w & 1;
    const int RB = wr * 64, CB = wc * 128;
    const int l15 = lane & 15, l4 = lane >> 4;
    const long rowbase = (long)blockIdx.x * BM;

    // stage: 12 x global_load_lds(16B) per thread; linear LDS dest,
    // XOR-swizzled global source (involution, bijective per row)
    auto STAGE = [&](int buf, int ct, int dt) {
        #pragma unroll
        for (int p = 0; p < 4; ++p) {               // x: 128 rows x 32 f32
            int f = p * 256 + t;
            int r = f >> 3, u = f & 7;              // 8 x 16B units per row
            const float* gp = x + (rowbase + r) * D_DIM + dt * DT + (u ^ (r & 7)) * 4;
            float* lb = &xs[buf][0][0] + (size_t)(p * 256 + w * 64) * 4;
            load_lds16(gp, lb);
        }
        #pragma unroll
        for (int p = 0; p < 4; ++p) {               // e hi: 256 codes x 32 bf16
            int f = p * 256 + t;
            int c = f >> 2, u = f & 3;              // 4 x 16B units per code
            const unsigned short* gp = ehi + (size_t)(ct * BN + c) * D_DIM + dt * DT
                                           + (u ^ ((c >> 1) & 3)) * 8;
            unsigned short* lb = &ehs[buf][0][0] + (size_t)(p * 256 + w * 64) * 8;
            load_lds16(gp, lb);
        }
        #pragma unroll
        for (int p = 0; p < 4; ++p) {               // e lo
            int f = p * 256 + t;
            int c = f >> 2, u = f & 3;
            const unsigned short* gp = elo + (size_t)(ct * BN + c) * D_DIM + dt * DT
                                           + (u ^ ((c >> 1) & 3)) * 8;
            unsigned short* lb = &els[buf][0][0] + (size_t)(p * 256 + w * 64) * 8;
            load_lds16(gp, lb);
        }
    };

    // prologue: enorm + first tile
    *(float4*)&enorm_s[t * 4] = ld4(enorm + t * 4);
    STAGE(0, 0, 0);

    float bestv[4][4];
    int   besti[4][4];
    #pragma unroll
    for (int i = 0; i < 4; ++i)
        #pragma unroll
        for (int j = 0; j < 4; ++j) { bestv[i][j] = 3.4e38f; besti[i][j] = 0; }

    __syncthreads();   // drains prologue staging (vmcnt0+lgkmcnt0)

    int cur = 0;
    #pragma unroll 1
    for (int ct = 0; ct < NCT; ++ct) {
        f32x4 acc[4][8];
        #pragma unroll
        for (int ri = 0; ri < 4; ++ri)
            #pragma unroll
            for (int cj = 0; cj < 8; ++cj) acc[ri][cj] = (f32x4){0.f, 0.f, 0.f, 0.f};

        #pragma unroll 1
        for (int dt = 0; dt < NDT; ++dt) {
            // issue next tile's staging before compute (latency hides under MFMA)
            if (!(ct == NCT - 1 && dt == NDT - 1)) {
                int nct = (dt == NDT - 1) ? ct + 1 : ct;
                int ndt = (dt + 1) & (NDT - 1);
                STAGE(cur ^ 1, nct, ndt);
            }
            // B fragments (bank-friendly via swizzled read)
            bf16x8 bh[8], bl[8];
            #pragma unroll
            for (int cj = 0; cj < 8; ++cj) {
                int code = CB + cj * 16 + l15;
                int ue = l4 ^ ((code >> 1) & 3);
                bh[cj] = *(const bf16x8*)((const char*)&ehs[cur][0][0] + code * 64 + ue * 16);
                bl[cj] = *(const bf16x8*)((const char*)&els[cur][0][0] + code * 64 + ue * 16);
            }
            // A fragments: fp32 -> hi/lo bf16, then 96 MFMA
            #pragma unroll
            for (int ri = 0; ri < 4; ++ri) {
                int row = RB + ri * 16 + l15;
                int s = l15 & 7;
                const f32x4* xrow = (const f32x4*)((const char*)&xs[cur][0][0] + row * 128);
                f32x4 a0 = xrow[(l4 * 2) ^ s];
                f32x4 a1 = xrow[(l4 * 2 + 1) ^ s];
                bf16x8 ah, al;
                cvt8(a0, a1, ah, al);
                #pragma unroll
                for (int cj = 0; cj < 8; ++cj) {
                    acc[ri][cj] = __builtin_amdgcn_mfma_f32_16x16x32_bf16(ah, bh[cj], acc[ri][cj], 0, 0, 0);
                    acc[ri][cj] = __builtin_amdgcn_mfma_f32_16x16x32_bf16(ah, bl[cj], acc[ri][cj], 0, 0, 0);
                    acc[ri][cj] = __builtin_amdgcn_mfma_f32_16x16x32_bf16(al, bh[cj], acc[ri][cj], 0, 0, 0);
                }
            }
            __syncthreads();   // full drain: staged tile ready, readers done
            cur ^= 1;
        }
        // fold this 256-code chunk into running (min, argmin); ascending c
        #pragma unroll
        for (int cj = 0; cj < 8; ++cj) {
            int c = ct * BN + CB + cj * 16 + l15;
            float en = enorm_s[c];
            #pragma unroll
            for (int ri = 0; ri < 4; ++ri)
                #pragma unroll
                for (int r = 0; r < 4; ++r) {
                    float dist = fmaf(-2.0f, acc[ri][cj][r], en);
                    if (dist < bestv[ri][r]) { bestv[ri][r] = dist; besti[ri][r] = c; }
                }
        }
    }

    // butterfly across the 16 lanes (l15) sharing each row
    #pragma unroll
    for (int ri = 0; ri < 4; ++ri)
        #pragma unroll
        for (int r = 0; r < 4; ++r) {
            float bv = bestv[ri][r];
            int bi = besti[ri][r];
            #pragma unroll
            for (int off = 1; off < 16; off <<= 1) {
                float ov = __shfl_xor(bv, off);
                int oi = __shfl_xor(bi, off);
                if (ov < bv || (ov == bv && oi < bi)) { bv = ov; bi = oi; }
            }
            if (l15 == 0) {
                int row = RB + ri * 16 + l4 * 4 + r;
                bestv_s[wc][row] = bv;
                besti_s[wc][row] = bi;
            }
        }
    __syncthreads();
    if (t < BM) {
        float v0 = bestv_s[0][t], v1 = bestv_s[1][t];
        int i0 = besti_s[0][t], i1 = besti_s[1][t];
        int bi = (v1 < v0 || (v1 == v0 && i1 < i0)) ? i1 : i0;
        long row = rowbase + t;
        idx_out[row] = bi;
        idxf_out[row] = (float)bi;
        atomicAdd(&cnt[bi], 1);
    }
}

// ---------------------------------------------------------------------------
// Kernel 2: exclusive prefix sum over K=1024 counts -> offsets + cursor copy
// ---------------------------------------------------------------------------
__global__ __launch_bounds__(1024)
void prefix_kernel(const int* __restrict__ cnt, int* __restrict__ offs,
                   int* __restrict__ cursor) {
    int t = threadIdx.x;
    int v = cnt[t];
    int s = v;
    #pragma unroll
    for (int off = 1; off < 64; off <<= 1) {
        int u = __shfl_up(s, off);
        if ((t & 63) >= off) s += u;
    }
    __shared__ int wsum[16], woff[16];
    if ((t & 63) == 63) wsum[t >> 6] = s;
    __syncthreads();
    if (t < 16) {
        int a = 0;
        for (int i = 0; i < t; ++i) a += wsum[i];
        woff[t] = a;
    }
    __syncthreads();
    int excl = s - v + woff[t >> 6];
    offs[t] = excl;
    cursor[t] = excl;
}

// ---------------------------------------------------------------------------
// Kernel 3: bucket-fill row ids (and their code) ordered by code
// ---------------------------------------------------------------------------
__global__ __launch_bounds__(256)
void fill_kernel(const int* __restrict__ idx, int* __restrict__ cursor,
                 int* __restrict__ order, int* __restrict__ key, int n) {
    int i = blockIdx.x * blockDim.x + threadIdx.x;
    if (i < n) {
        int k = idx[i];
        int pos = atomicAdd(&cursor[k], 1);
        order[pos] = i;
        key[pos] = k;
    }
}

// ---------------------------------------------------------------------------
// Kernel 4: fused per-chunk embsum (segment flush) + quantized STE + loss.
// 64 code-sorted rows per block; load-balanced regardless of cluster skew.
// ---------------------------------------------------------------------------
__global__ __launch_bounds__(256)
void chunk_kernel(const float* __restrict__ x, const float* __restrict__ emb,
                  const int* __restrict__ order, const int* __restrict__ key,
                  float* __restrict__ qst_out, float* __restrict__ embsum,
                  float* __restrict__ partials, int n) {
    const int t = threadIdx.x;
    const int lane = t & 63;
    const int w = t >> 6;
    const long base = (long)blockIdx.x * CH;
    float lsum = 0.0f;
    int cur_k = -1;
    float4 s = {0.f, 0.f, 0.f, 0.f};
    for (int i = w; i < CH; i += 4) {
        long pos = base + i;
        if (pos >= n) break;
        int row = order[pos];
        int k = key[pos];
        float4 xv = ld4(x + (size_t)row * D_DIM + lane * 4);
        float4 qv = ld4(emb + (size_t)k * D_DIM + lane * 4);
        if (k != cur_k) {
            if (cur_k >= 0) {
                float* p = embsum + (size_t)cur_k * D_DIM + lane * 4;
                atomicAdd(p + 0, s.x); atomicAdd(p + 1, s.y);
                atomicAdd(p + 2, s.z); atomicAdd(p + 3, s.w);
            }
            s = {0.f, 0.f, 0.f, 0.f};
            cur_k = k;
        }
        s.x += xv.x; s.y += xv.y; s.z += xv.z; s.w += xv.w;
        float4 o;   // x + (q - x), exactly as the reference computes the STE
        o.x = xv.x + (qv.x - xv.x);
        o.y = xv.y + (qv.y - xv.y);
        o.z = xv.z + (qv.z - xv.z);
        o.w = xv.w + (qv.w - xv.w);
        st4(qst_out + (size_t)row * D_DIM + lane * 4, o);
        float dx = xv.x - qv.x, dy = xv.y - qv.y, dz = xv.z - qv.z, dw = xv.w - qv.w;
        lsum += dx * dx + dy * dy + dz * dz + dw * dw;
    }
    if (cur_k >= 0) {
        float* p = embsum + (size_t)cur_k * D_DIM + lane * 4;
        atomicAdd(p + 0, s.x); atomicAdd(p + 1, s.y);
        atomicAdd(p + 2, s.z); atomicAdd(p + 3, s.w);
    }
    #pragma unroll
    for (int off = 32; off; off >>= 1) lsum += __shfl_down(lsum, off);
    __shared__ float wsum[4];
    if (lane == 0) wsum[w] = lsum;
    __syncthreads();
    if (t == 0) partials[blockIdx.x] = wsum[0] + wsum[1] + wsum[2] + wsum[3];
}

// ---------------------------------------------------------------------------
// Kernel 5: cluster-size EMA + Laplace-smoothed denominator (one block)
// ---------------------------------------------------------------------------
__global__ __launch_bounds__(1024)
void cs_kernel(const float* __restrict__ cs_in, const int* __restrict__ counts,
               float* __restrict__ ncs_out, float* __restrict__ cs_ws, int K) {
    const float DECAY = 0.99f, OMD = 0.01f, EPSF = 1e-5f;
    int t = threadIdx.x;
    float ncs = 0.0f;
    if (t < K) {
        ncs = cs_in[t] * DECAY + (float)counts[t] * OMD;
        ncs_out[t] = ncs;
    }
    float s = ncs;
    #pragma unroll
    for (int off = 32; off; off >>= 1) s += __shfl_down(s, off);
    __shared__ float red[16];
    __shared__ float n_sh;
    if ((t & 63) == 0) red[t >> 6] = s;
    __syncthreads();
    if (t == 0) {
        float n = 0.0f;
        for (int i = 0; i < (int)(blockDim.x >> 6); ++i) n += red[i];
        n_sh = n;
    }
    __syncthreads();
    if (t < K) {
        float n = n_sh;
        cs_ws[t] = (ncs + EPSF) / (n + (float)K * EPSF) * n;
    }
}

// ---------------------------------------------------------------------------
// Kernel 6: embedding_avg EMA + normalized new_embedding
// ---------------------------------------------------------------------------
__global__ __launch_bounds__(256)
void emb_kernel(const float* __restrict__ avg_in, const float* __restrict__ embsum,
                const float* __restrict__ cs_ws,
                float* __restrict__ nemb_out, float* __restrict__ navg_out) {
    const float DECAY = 0.99f, OMD = 0.01f;
    int id = blockIdx.x * 256 + threadIdx.x;
    int k = id >> 6;
    float4 s = ld4(embsum + (size_t)id * 4);
    float4 a = ld4(avg_in + (size_t)id * 4);
    float4 na;
    na.x = a.x * DECAY + s.x * OMD;
    na.y = a.y * DECAY + s.y * OMD;
    na.z = a.z * DECAY + s.z * OMD;
    na.w = a.w * DECAY + s.w * OMD;
    st4(navg_out + (size_t)id * 4, na);
    float c = cs_ws[k];
    float4 ne;
    ne.x = na.x / c; ne.y = na.y / c; ne.z = na.z / c; ne.w = na.w / c;
    st4(nemb_out + (size_t)id * 4, ne);
}

// ---------------------------------------------------------------------------
// Kernel 7: final loss reduction (deterministic, one block)
// ---------------------------------------------------------------------------
__global__ __launch_bounds__(256)
void loss_kernel(const float* __restrict__ partials, int n,
                 float* __restrict__ out, float scale) {
    double s = 0.0;
    for (int i = threadIdx.x; i < n; i += 256) s += (double)partials[i];
    #pragma unroll
    for (int off = 32; off; off >>= 1) s += __shfl_down(s, off);
    __shared__ double red[4];
    int lane = threadIdx.x & 63, wid = threadIdx.x >> 6;
    if (lane == 0) red[wid] = s;
    __syncthreads();
    if (threadIdx.x == 0)
        out[0] = (float)((red[0] + red[1] + red[2] + red[3]) * (double)scale);
}

// ---------------------------------------------------------------------------
extern "C" void kernel_launch(void* const* d_in, const int* in_sizes, int n_in,
                              void* d_out, int out_size, void* d_ws, size_t ws_size,
                              hipStream_t stream) {
    const float* x    = (const float*)d_in[0];   // [N, 256]
    const float* emb  = (const float*)d_in[1];   // [1024, 256]
    const float* csz  = (const float*)d_in[2];   // [1024]
    const float* eavg = (const float*)d_in[3];   // [1024, 256]
    const int D = D_DIM, K = K_CODES;
    const int N = in_sizes[0] / D;

    float* out      = (float*)d_out;
    float* out_q    = out;                        // N*D  quantized_st
    float* out_loss = out_q + (size_t)N * D;      // 1    loss
    float* out_idx  = out_loss + 1;               // N    encoding_indices (as float)
    float* out_nemb = out_idx + N;                // K*D  new_embedding
    float* out_ncs  = out_nemb + (size_t)K * D;   // K    new_cluster_size
    float* out_navg = out_ncs + K;                // K*D  new_embedding_avg

    char* wsp = (char*)d_ws;
    int*   ws_idx    = (int*)wsp;            wsp += sizeof(int) * (size_t)N;
    int*   ws_order  = (int*)wsp;            wsp += sizeof(int) * (size_t)N;
    int*   ws_key    = (int*)wsp;            wsp += sizeof(int) * (size_t)N;
    float* ws_enorm  = (float*)wsp;          wsp += sizeof(float) * K;
    int*   ws_cnt    = (int*)wsp;            wsp += sizeof(int) * K;
    int*   ws_offs   = (int*)wsp;            wsp += sizeof(int) * K;
    int*   ws_cursor = (int*)wsp;            wsp += sizeof(int) * K;
    float* ws_cs     = (float*)wsp;          wsp += sizeof(float) * K;
    float* ws_embsum = (float*)wsp;          wsp += sizeof(float) * (size_t)K * D;
    unsigned short* ws_ehi = (unsigned short*)wsp;  wsp += sizeof(unsigned short) * (size_t)K * D;
    unsigned short* ws_elo = (unsigned short*)wsp;  wsp += sizeof(unsigned short) * (size_t)K * D;
    float* ws_part   = (float*)wsp;          // N/CH floats

    hipMemsetAsync(ws_cnt, 0, sizeof(int) * K, stream);
    hipMemsetAsync(ws_embsum, 0, sizeof(float) * (size_t)K * D, stream);

    splitnorm_kernel<<<K / 4, 256, 0, stream>>>(emb, ws_ehi, ws_elo, ws_enorm);
    argmin_mfma<<<N / BM, 256, 0, stream>>>(x, ws_ehi, ws_elo, ws_enorm,
                                            ws_idx, out_idx, ws_cnt);
    prefix_kernel<<<1, 1024, 0, stream>>>(ws_cnt, ws_offs, ws_cursor);
    fill_kernel<<<(N + 255) / 256, 256, 0, stream>>>(ws_idx, ws_cursor, ws_order,
                                                     ws_key, N);
    const int NCHUNK = (N + CH - 1) / CH;   // 2048
    chunk_kernel<<<NCHUNK, 256, 0, stream>>>(x, emb, ws_order, ws_key, out_q,
                                             ws_embsum, ws_part, N);
    cs_kernel<<<1, 1024, 0, stream>>>(csz, ws_cnt, out_ncs, ws_cs, K);
    emb_kernel<<<(K * D / 4) / 256, 256, 0, stream>>>(eavg, ws_embsum, ws_cs,
                                                      out_nemb, out_navg);
    loss_kernel<<<1, 256, 0, stream>>>(ws_part, NCHUNK, out_loss,
                                       1.0f / ((float)N * (float)D));
}

// Round 6
// 399.382 us; speedup vs baseline: 4.5315x; 1.3299x over previous
//
#include <hip/hip_runtime.h>

#define D_DIM 256
#define K_CODES 1024
#define BM 128               // rows per block (4 waves x 32 rows)
#define CCH 32               // codes per LDS chunk
#define NCH (K_CODES / CCH)  // 32 chunks
#define CH 64                // rows per chunk block (fused embsum/quant)

typedef short bf16x8 __attribute__((ext_vector_type(8)));   // 8 bf16 = 4 VGPRs
typedef float f32x4  __attribute__((ext_vector_type(4)));

__device__ __forceinline__ const float4& ld4(const float* p) {
    return *reinterpret_cast<const float4*>(p);
}
__device__ __forceinline__ void st4(float* p, const float4& v) {
    *reinterpret_cast<float4*>(p) = v;
}
// round-to-nearest-even fp32 -> bf16 (as ushort)
__device__ __forceinline__ unsigned short f2bf(float f) {
    union { float f; unsigned u; } c{f};
    unsigned r = c.u + 0x7FFFu + ((c.u >> 16) & 1u);
    return (unsigned short)(r >> 16);
}
__device__ __forceinline__ float bf2f(unsigned short h) {
    union { unsigned u; float f; } c{(unsigned)h << 16};
    return c.f;
}
// 8 fp32 -> hi/lo bf16x8 fragments
__device__ __forceinline__ void cvt8(f32x4 a0, f32x4 a1, bf16x8& hi, bf16x8& lo) {
    #pragma unroll
    for (int j = 0; j < 4; ++j) {
        unsigned short h = f2bf(a0[j]);
        unsigned short l = f2bf(a0[j] - bf2f(h));
        hi[j] = (short)h; lo[j] = (short)l;
    }
    #pragma unroll
    for (int j = 0; j < 4; ++j) {
        unsigned short h = f2bf(a1[j]);
        unsigned short l = f2bf(a1[j] - bf2f(h));
        hi[4 + j] = (short)h; lo[4 + j] = (short)l;
    }
}
// async global->LDS, 16B per lane, wave-uniform LDS base
typedef __attribute__((address_space(3))) void lds_void;
typedef const __attribute__((address_space(1))) void glb_void;
__device__ __forceinline__ void load_lds16(const void* g, void* l) {
    __builtin_amdgcn_global_load_lds((glb_void*)g, (lds_void*)l, 16, 0, 0);
}

// ---------------------------------------------------------------------------
// Kernel 0: split emb into bf16 hi/lo + fp32 norms. One wave per code.
// ---------------------------------------------------------------------------
__global__ __launch_bounds__(256)
void splitnorm_kernel(const float* __restrict__ emb, unsigned short* __restrict__ ehi,
                      unsigned short* __restrict__ elo, float* __restrict__ enorm) {
    int gid = blockIdx.x * blockDim.x + threadIdx.x;
    int k = gid >> 6, lane = gid & 63;
    if (k >= K_CODES) return;
    float4 v = ld4(emb + (size_t)k * D_DIM + lane * 4);
    float nv = v.x * v.x + v.y * v.y + v.z * v.z + v.w * v.w;
    unsigned short h[4], l[4];
    float vv[4] = {v.x, v.y, v.z, v.w};
    #pragma unroll
    for (int j = 0; j < 4; ++j) {
        h[j] = f2bf(vv[j]);
        l[j] = f2bf(vv[j] - bf2f(h[j]));
    }
    uint2 hp, lp;
    hp.x = (unsigned)h[0] | ((unsigned)h[1] << 16);
    hp.y = (unsigned)h[2] | ((unsigned)h[3] << 16);
    lp.x = (unsigned)l[0] | ((unsigned)l[1] << 16);
    lp.y = (unsigned)l[2] | ((unsigned)l[3] << 16);
    *(uint2*)(ehi + (size_t)k * D_DIM + lane * 4) = hp;
    *(uint2*)(elo + (size_t)k * D_DIM + lane * 4) = lp;
    #pragma unroll
    for (int off = 32; off; off >>= 1) nv += __shfl_down(nv, off);
    if (lane == 0) enorm[k] = nv;
}

// ---------------------------------------------------------------------------
// Kernel 1: MFMA distance + argmin, x-stationary.
// 4 waves x 32 rows; per wave: x hi/lo A-frags for all 256 dims live in
// registers (converted once). LDS double-buffers a 32-code e hi/lo chunk
// (L2-resident source). Each wave covers all codes for its rows -> direct
// writeback, no cross-wave reduce. XOR source-swizzle on e staging.
// ---------------------------------------------------------------------------
__global__ __launch_bounds__(256, 2)
void argmin_mfma(const float* __restrict__ x,
                 const unsigned short* __restrict__ ehi,
                 const unsigned short* __restrict__ elo,
                 const float* __restrict__ enorm,
                 int* __restrict__ idx_out, float* __restrict__ idxf_out,
                 int* __restrict__ cnt) {
    __shared__ __align__(16) unsigned short eh_s[2][CCH][D_DIM];  // 32 KB
    __shared__ __align__(16) unsigned short el_s[2][CCH][D_DIM];  // 32 KB
    __shared__ __align__(16) float enorm_s[K_CODES];              // 4 KB

    const int t = threadIdx.x;
    const int lane = t & 63;
    const int w = t >> 6;
    const int l15 = lane & 15, l4 = lane >> 4;
    const long rowbase = (long)blockIdx.x * BM + w * 32;

    // stage one 32-code chunk (hi+lo), linear LDS dest, swizzled global src
    auto STAGE = [&](int buf, int ch) {
        #pragma unroll
        for (int p = 0; p < 4; ++p) {
            int f = p * 256 + t;            // 1024 16B-units per array
            int c = f >> 5, u = f & 31;     // 32 units per 512B code row
            int us = u ^ (c & 7);           // involution within the row
            size_t gofs = (size_t)(ch * CCH + c) * D_DIM + us * 8;
            unsigned short* lb = (unsigned short*)&eh_s[buf][0][0] + (size_t)f * 8;
            unsigned short* lb2 = (unsigned short*)&el_s[buf][0][0] + (size_t)f * 8;
            load_lds16(ehi + gofs, lb);
            load_lds16(elo + gofs, lb2);
        }
    };

    STAGE(0, 0);   // async; latency hides under the x prologue below

    // x A-fragments -> registers (hi/lo), all 256 dims for this wave's 32 rows
    bf16x8 xah[2][8], xal[2][8];
    #pragma unroll
    for (int rg = 0; rg < 2; ++rg)
        #pragma unroll
        for (int df = 0; df < 8; ++df) {
            const float* xp = x + (rowbase + rg * 16 + l15) * D_DIM + df * 32 + l4 * 8;
            f32x4 a0 = *(const f32x4*)xp;
            f32x4 a1 = *(const f32x4*)(xp + 4);
            cvt8(a0, a1, xah[rg][df], xal[rg][df]);
        }
    *(float4*)&enorm_s[t * 4] = ld4(enorm + t * 4);

    float bestv[2][4];
    int   besti[2][4];
    #pragma unroll
    for (int rg = 0; rg < 2; ++rg)
        #pragma unroll
        for (int r = 0; r < 4; ++r) { bestv[rg][r] = 3.4e38f; besti[rg][r] = 0; }

    __syncthreads();   // chunk 0 + enorm staged

    int cur = 0;
    #pragma unroll 1
    for (int ch = 0; ch < NCH; ++ch) {
        if (ch < NCH - 1) STAGE(cur ^ 1, ch + 1);   // issue before compute
        f32x4 acc[2][2];   // [rowgroup][cj]
        #pragma unroll
        for (int rg = 0; rg < 2; ++rg)
            #pragma unroll
            for (int cj = 0; cj < 2; ++cj) acc[rg][cj] = (f32x4){0.f, 0.f, 0.f, 0.f};

        #pragma unroll
        for (int df = 0; df < 8; ++df) {
            #pragma unroll
            for (int cj = 0; cj < 2; ++cj) {
                int lc = cj * 16 + l15;
                int us = (df * 4 + l4) ^ (lc & 7);
                bf16x8 bh = *(const bf16x8*)((const char*)&eh_s[cur][0][0] + lc * 512 + us * 16);
                bf16x8 bl = *(const bf16x8*)((const char*)&el_s[cur][0][0] + lc * 512 + us * 16);
                #pragma unroll
                for (int rg = 0; rg < 2; ++rg) {
                    acc[rg][cj] = __builtin_amdgcn_mfma_f32_16x16x32_bf16(xah[rg][df], bh, acc[rg][cj], 0, 0, 0);
                    acc[rg][cj] = __builtin_amdgcn_mfma_f32_16x16x32_bf16(xah[rg][df], bl, acc[rg][cj], 0, 0, 0);
                    acc[rg][cj] = __builtin_amdgcn_mfma_f32_16x16x32_bf16(xal[rg][df], bh, acc[rg][cj], 0, 0, 0);
                }
            }
        }
        // fold 32 codes into running (min, argmin); ascending code order
        #pragma unroll
        for (int cj = 0; cj < 2; ++cj) {
            int c = ch * CCH + cj * 16 + l15;
            float en = enorm_s[c];
            #pragma unroll
            for (int rg = 0; rg < 2; ++rg)
                #pragma unroll
                for (int r = 0; r < 4; ++r) {
                    float dist = fmaf(-2.0f, acc[rg][cj][r], en);
                    if (dist < bestv[rg][r]) { bestv[rg][r] = dist; besti[rg][r] = c; }
                }
        }
        __syncthreads();   // staged chunk ready; readers done before overwrite
        cur ^= 1;
    }

    // butterfly across the 16 l15-lanes (same row group of 4 codes sets)
    #pragma unroll
    for (int rg = 0; rg < 2; ++rg)
        #pragma unroll
        for (int r = 0; r < 4; ++r) {
            float bv = bestv[rg][r];
            int bi = besti[rg][r];
            #pragma unroll
            for (int off = 1; off < 16; off <<= 1) {
                float ov = __shfl_xor(bv, off);
                int oi = __shfl_xor(bi, off);
                if (ov < bv || (ov == bv && oi < bi)) { bv = ov; bi = oi; }
            }
            if (l15 == 0) {
                long row = rowbase + rg * 16 + l4 * 4 + r;
                idx_out[row] = bi;
                idxf_out[row] = (float)bi;
                atomicAdd(&cnt[bi], 1);
            }
        }
}

// ---------------------------------------------------------------------------
// Kernel 2: exclusive prefix sum over K=1024 counts -> offsets + cursor copy
// ---------------------------------------------------------------------------
__global__ __launch_bounds__(1024)
void prefix_kernel(const int* __restrict__ cnt, int* __restrict__ offs,
                   int* __restrict__ cursor) {
    int t = threadIdx.x;
    int v = cnt[t];
    int s = v;
    #pragma unroll
    for (int off = 1; off < 64; off <<= 1) {
        int u = __shfl_up(s, off);
        if ((t & 63) >= off) s += u;
    }
    __shared__ int wsum[16], woff[16];
    if ((t & 63) == 63) wsum[t >> 6] = s;
    __syncthreads();
    if (t < 16) {
        int a = 0;
        for (int i = 0; i < t; ++i) a += wsum[i];
        woff[t] = a;
    }
    __syncthreads();
    int excl = s - v + woff[t >> 6];
    offs[t] = excl;
    cursor[t] = excl;
}

// ---------------------------------------------------------------------------
// Kernel 3: bucket-fill row ids (and their code) ordered by code
// ---------------------------------------------------------------------------
__global__ __launch_bounds__(256)
void fill_kernel(const int* __restrict__ idx, int* __restrict__ cursor,
                 int* __restrict__ order, int* __restrict__ key, int n) {
    int i = blockIdx.x * blockDim.x + threadIdx.x;
    if (i < n) {
        int k = idx[i];
        int pos = atomicAdd(&cursor[k], 1);
        order[pos] = i;
        key[pos] = k;
    }
}

// ---------------------------------------------------------------------------
// Kernel 4: fused per-chunk embsum (segment flush) + quantized STE + loss.
// 64 code-sorted rows per block; load-balanced regardless of cluster skew.
// ---------------------------------------------------------------------------
__global__ __launch_bounds__(256)
void chunk_kernel(const float* __restrict__ x, const float* __restrict__ emb,
                  const int* __restrict__ order, const int* __restrict__ key,
                  float* __restrict__ qst_out, float* __restrict__ embsum,
                  float* __restrict__ partials, int n) {
    const int t = threadIdx.x;
    const int lane = t & 63;
    const int w = t >> 6;
    const long base = (long)blockIdx.x * CH;
    float lsum = 0.0f;
    int cur_k = -1;
    float4 s = {0.f, 0.f, 0.f, 0.f};
    for (int i = w; i < CH; i += 4) {
        long pos = base + i;
        if (pos >= n) break;
        int row = order[pos];
        int k = key[pos];
        float4 xv = ld4(x + (size_t)row * D_DIM + lane * 4);
        float4 qv = ld4(emb + (size_t)k * D_DIM + lane * 4);
        if (k != cur_k) {
            if (cur_k >= 0) {
                float* p = embsum + (size_t)cur_k * D_DIM + lane * 4;
                atomicAdd(p + 0, s.x); atomicAdd(p + 1, s.y);
                atomicAdd(p + 2, s.z); atomicAdd(p + 3, s.w);
            }
            s = {0.f, 0.f, 0.f, 0.f};
            cur_k = k;
        }
        s.x += xv.x; s.y += xv.y; s.z += xv.z; s.w += xv.w;
        float4 o;   // x + (q - x), exactly as the reference computes the STE
        o.x = xv.x + (qv.x - xv.x);
        o.y = xv.y + (qv.y - xv.y);
        o.z = xv.z + (qv.z - xv.z);
        o.w = xv.w + (qv.w - xv.w);
        st4(qst_out + (size_t)row * D_DIM + lane * 4, o);
        float dx = xv.x - qv.x, dy = xv.y - qv.y, dz = xv.z - qv.z, dw = xv.w - qv.w;
        lsum += dx * dx + dy * dy + dz * dz + dw * dw;
    }
    if (cur_k >= 0) {
        float* p = embsum + (size_t)cur_k * D_DIM + lane * 4;
        atomicAdd(p + 0, s.x); atomicAdd(p + 1, s.y);
        atomicAdd(p + 2, s.z); atomicAdd(p + 3, s.w);
    }
    #pragma unroll
    for (int off = 32; off; off >>= 1) lsum += __shfl_down(lsum, off);
    __shared__ float wsum[4];
    if (lane == 0) wsum[w] = lsum;
    __syncthreads();
    if (t == 0) partials[blockIdx.x] = wsum[0] + wsum[1] + wsum[2] + wsum[3];
}

// ---------------------------------------------------------------------------
// Kernel 5: cluster-size EMA + Laplace-smoothed denominator (one block)
// ---------------------------------------------------------------------------
__global__ __launch_bounds__(1024)
void cs_kernel(const float* __restrict__ cs_in, const int* __restrict__ counts,
               float* __restrict__ ncs_out, float* __restrict__ cs_ws, int K) {
    const float DECAY = 0.99f, OMD = 0.01f, EPSF = 1e-5f;
    int t = threadIdx.x;
    float ncs = 0.0f;
    if (t < K) {
        ncs = cs_in[t] * DECAY + (float)counts[t] * OMD;
        ncs_out[t] = ncs;
    }
    float s = ncs;
    #pragma unroll
    for (int off = 32; off; off >>= 1) s += __shfl_down(s, off);
    __shared__ float red[16];
    __shared__ float n_sh;
    if ((t & 63) == 0) red[t >> 6] = s;
    __syncthreads();
    if (t == 0) {
        float n = 0.0f;
        for (int i = 0; i < (int)(blockDim.x >> 6); ++i) n += red[i];
        n_sh = n;
    }
    __syncthreads();
    if (t < K) {
        float n = n_sh;
        cs_ws[t] = (ncs + EPSF) / (n + (float)K * EPSF) * n;
    }
}

// ---------------------------------------------------------------------------
// Kernel 6: embedding_avg EMA + normalized new_embedding
// ---------------------------------------------------------------------------
__global__ __launch_bounds__(256)
void emb_kernel(const float* __restrict__ avg_in, const float* __restrict__ embsum,
                const float* __restrict__ cs_ws,
                float* __restrict__ nemb_out, float* __restrict__ navg_out) {
    const float DECAY = 0.99f, OMD = 0.01f;
    int id = blockIdx.x * 256 + threadIdx.x;
    int k = id >> 6;
    float4 s = ld4(embsum + (size_t)id * 4);
    float4 a = ld4(avg_in + (size_t)id * 4);
    float4 na;
    na.x = a.x * DECAY + s.x * OMD;
    na.y = a.y * DECAY + s.y * OMD;
    na.z = a.z * DECAY + s.z * OMD;
    na.w = a.w * DECAY + s.w * OMD;
    st4(navg_out + (size_t)id * 4, na);
    float c = cs_ws[k];
    float4 ne;
    ne.x = na.x / c; ne.y = na.y / c; ne.z = na.z / c; ne.w = na.w / c;
    st4(nemb_out + (size_t)id * 4, ne);
}

// ---------------------------------------------------------------------------
// Kernel 7: final loss reduction (deterministic, one block)
// ---------------------------------------------------------------------------
__global__ __launch_bounds__(256)
void loss_kernel(const float* __restrict__ partials, int n,
                 float* __restrict__ out, float scale) {
    double s = 0.0;
    for (int i = threadIdx.x; i < n; i += 256) s += (double)partials[i];
    #pragma unroll
    for (int off = 32; off; off >>= 1) s += __shfl_down(s, off);
    __shared__ double red[4];
    int lane = threadIdx.x & 63, wid = threadIdx.x >> 6;
    if (lane == 0) red[wid] = s;
    __syncthreads();
    if (threadIdx.x == 0)
        out[0] = (float)((red[0] + red[1] + red[2] + red[3]) * (double)scale);
}

// ---------------------------------------------------------------------------
extern "C" void kernel_launch(void* const* d_in, const int* in_sizes, int n_in,
                              void* d_out, int out_size, void* d_ws, size_t ws_size,
                              hipStream_t stream) {
    const float* x    = (const float*)d_in[0];   // [N, 256]
    const float* emb  = (const float*)d_in[1];   // [1024, 256]
    const float* csz  = (const float*)d_in[2];   // [1024]
    const float* eavg = (const float*)d_in[3];   // [1024, 256]
    const int D = D_DIM, K = K_CODES;
    const int N = in_sizes[0] / D;

    float* out      = (float*)d_out;
    float* out_q    = out;                        // N*D  quantized_st
    float* out_loss = out_q + (size_t)N * D;      // 1    loss
    float* out_idx  = out_loss + 1;               // N    encoding_indices (as float)
    float* out_nemb = out_idx + N;                // K*D  new_embedding
    float* out_ncs  = out_nemb + (size_t)K * D;   // K    new_cluster_size
    float* out_navg = out_ncs + K;                // K*D  new_embedding_avg

    char* wsp = (char*)d_ws;
    int*   ws_idx    = (int*)wsp;            wsp += sizeof(int) * (size_t)N;
    int*   ws_order  = (int*)wsp;            wsp += sizeof(int) * (size_t)N;
    int*   ws_key    = (int*)wsp;            wsp += sizeof(int) * (size_t)N;
    float* ws_enorm  = (float*)wsp;          wsp += sizeof(float) * K;
    int*   ws_cnt    = (int*)wsp;            wsp += sizeof(int) * K;
    int*   ws_offs   = (int*)wsp;            wsp += sizeof(int) * K;
    int*   ws_cursor = (int*)wsp;            wsp += sizeof(int) * K;
    float* ws_cs     = (float*)wsp;          wsp += sizeof(float) * K;
    float* ws_embsum = (float*)wsp;          wsp += sizeof(float) * (size_t)K * D;
    unsigned short* ws_ehi = (unsigned short*)wsp;  wsp += sizeof(unsigned short) * (size_t)K * D;
    unsigned short* ws_elo = (unsigned short*)wsp;  wsp += sizeof(unsigned short) * (size_t)K * D;
    float* ws_part   = (float*)wsp;          // N/CH floats

    hipMemsetAsync(ws_cnt, 0, sizeof(int) * K, stream);
    hipMemsetAsync(ws_embsum, 0, sizeof(float) * (size_t)K * D, stream);

    splitnorm_kernel<<<K / 4, 256, 0, stream>>>(emb, ws_ehi, ws_elo, ws_enorm);
    argmin_mfma<<<N / BM, 256, 0, stream>>>(x, ws_ehi, ws_elo, ws_enorm,
                                            ws_idx, out_idx, ws_cnt);
    prefix_kernel<<<1, 1024, 0, stream>>>(ws_cnt, ws_offs, ws_cursor);
    fill_kernel<<<(N + 255) / 256, 256, 0, stream>>>(ws_idx, ws_cursor, ws_order,
                                                     ws_key, N);
    const int NCHUNK = (N + CH - 1) / CH;   // 2048
    chunk_kernel<<<NCHUNK, 256, 0, stream>>>(x, emb, ws_order, ws_key, out_q,
                                             ws_embsum, ws_part, N);
    cs_kernel<<<1, 1024, 0, stream>>>(csz, ws_cnt, out_ncs, ws_cs, K);
    emb_kernel<<<(K * D / 4) / 256, 256, 0, stream>>>(eavg, ws_embsum, ws_cs,
                                                      out_nemb, out_navg);
    loss_kernel<<<1, 256, 0, stream>>>(ws_part, NCHUNK, out_loss,
                                       1.0f / ((float)N * (float)D));
}